// Round 4
// baseline (3152.941 us; speedup 1.0000x reference)
//
#include <hip/hip_runtime.h>
#include <type_traits>

#define N_ATOMS 256
#define N_MOL 4
#define N_PAIRS 8192
#define KE_C 14.3996
#define ALPHA_C 0.3
#define CUTOFF_C 6.0
#define NBLK 912

constexpr double PI_D    = 3.14159265358979323846;
constexpr double TWOSQPI = 1.12837916709551257390; // 2/sqrt(pi)
#define AL_F 0.3f
#define TWOSQPI_F 1.12837917f
#define K1_F 0.33851375f    // TWOSQPI*ALPHA
#define IAS_F 1.8806320f    // 1/(ALPHA*sqrt(pi))

// ---------------- fast fp32 erfc (rel err ~1e-6 with __expf) ----------------
__device__ __forceinline__ float fast_erfcf(float x){
  float ax = fabsf(x);
  float t = __fdividef(1.0f, fmaf(0.5f, ax, 1.0f));
  float p = 0.17087277f;
  p = fmaf(p, t, -0.82215223f);
  p = fmaf(p, t,  1.48851587f);
  p = fmaf(p, t, -1.13520398f);
  p = fmaf(p, t,  0.27886807f);
  p = fmaf(p, t, -0.18628806f);
  p = fmaf(p, t,  0.09678418f);
  p = fmaf(p, t,  0.37409196f);
  p = fmaf(p, t,  1.00002368f);
  p = fmaf(p, t, -1.26551223f);
  float ans = t*__expf(fmaf(-ax, ax, p));
  return x >= 0.0f ? ans : 2.0f - ans;
}

// ---------------- dual numbers (fp64, Born HVP) -----------------------------
struct Dd {
  double v, t;
  __device__ Dd() {}
  __device__ Dd(double v_) : v(v_), t(0.0) {}
  __device__ Dd(double v_, double t_) : v(v_), t(t_) {}
};
__device__ inline Dd operator+(Dd a, Dd b){ return Dd(a.v+b.v, a.t+b.t); }
__device__ inline Dd operator+(Dd a, double b){ return Dd(a.v+b, a.t); }
__device__ inline Dd operator-(Dd a, Dd b){ return Dd(a.v-b.v, a.t-b.t); }
__device__ inline Dd operator*(Dd a, Dd b){ return Dd(a.v*b.v, a.t*b.v + a.v*b.t); }
__device__ inline Dd operator*(double a, Dd b){ return Dd(a*b.v, a*b.t); }
__device__ inline double fsqrt(double a){ return sqrt(a); }
__device__ inline Dd     fsqrt(Dd a){ double s=sqrt(a.v); return Dd(s, a.t*0.5/s); }
__device__ inline double finv(double a){ return 1.0/a; }
__device__ inline Dd     finv(Dd a){ double iv=1.0/a.v; return Dd(iv, -a.t*iv*iv); }
__device__ inline double fpown(double a, double e){ return pow(a, e); }
__device__ inline Dd     fpown(Dd a, double e){ double p=pow(a.v,e); return Dd(p, a.t*e*p/a.v); }
__device__ inline double gval(double a){ return a; }
__device__ inline double gval(Dd a){ return a.v; }
__device__ inline double pick(double a){ return a; }
__device__ inline double pick(Dd a){ return a.t; }
template<class T> __device__ inline T loadP(const double* Rs, const double* V, int idx){
  if constexpr (std::is_same<T,double>::value) return Rs[idx];
  else return Dd(Rs[idx], V[idx]);
}

__device__ inline double cell_area(const float* cell){
  double a0=cell[0], a1=cell[1], a2=cell[2];
  double b0=cell[3], b1=cell[4], b2=cell[5];
  double cx=a1*b2-a2*b1, cy=a2*b0-a0*b2, cz=a0*b1-a1*b0;
  return sqrt(cx*cx+cy*cy+cz*cz);
}

// ---------------- device-scope grid barrier ---------------------------------
__device__ __forceinline__ void grid_barrier(int* cnt, int* gen){
  __syncthreads();
  if (threadIdx.x == 0){
    __threadfence();
    int g = __hip_atomic_load(gen, __ATOMIC_RELAXED, __HIP_MEMORY_SCOPE_AGENT);
    int old = __hip_atomic_fetch_add(cnt, 1, __ATOMIC_ACQ_REL, __HIP_MEMORY_SCOPE_AGENT);
    if (old == NBLK - 1){
      __hip_atomic_store(cnt, 0, __ATOMIC_RELAXED, __HIP_MEMORY_SCOPE_AGENT);
      __hip_atomic_fetch_add(gen, 1, __ATOMIC_RELEASE, __HIP_MEMORY_SCOPE_AGENT);
    } else {
      while (__hip_atomic_load(gen, __ATOMIC_ACQUIRE, __HIP_MEMORY_SCOPE_AGENT) == g)
        __builtin_amdgcn_s_sleep(2);
    }
    __threadfence();
  }
  __syncthreads();
}

// ---------------- pass body (P2=0: grad+energies; P2=1: HVP) ----------------
template<int P2>
__device__ void pass_body(int b, int i, const double* Rs, const double* V,
    const float* q, const float* offs, const float* r0a, const float* na,
    const int* ii, const int* jj, const int* im,
    const float* recipc, const float* cell, const float4* tab,
    double* gbase, double* scal, double* sh){
  double* g = gbase + (b & 7)*768;
  float* f = (float*)sh;
  double* red = sh + 128;
  if (b < 672) {
    // ---- kspace: kk = b>>3, 32-j chunk jc = b&7 ----
    int kk = b >> 3, jc = b & 7;
    double b0 = (double)(kk/13 - 6), b1d = (double)(kk%13 - 6);
    double TP = 2.0*PI_D;
    double h0d = TP*(b0*(double)recipc[0] + b1d*(double)recipc[3]);
    double h1d = TP*(b0*(double)recipc[1] + b1d*(double)recipc[4]);
    double h2d = TP*(b0*(double)recipc[2] + b1d*(double)recipc[5]);
    double kapd = sqrt(h0d*h0d + h1d*h1d + h2d*h2d);
    float A    = (float)(kapd/(2.0*ALPHA_C));
    float ikap = (float)(1.0/kapd);
    float kapf = (float)kapd;
    float *kc=f, *ksn=f+32, *kE=f+64, *kiE=f+96, *kz=f+128, *kq=f+160,
          *kdp=f+192, *kvz=f+224;
    if (i < 32) {
      int j = jc*32 + i;
      float4 t = tab[kk*256+j];
      kc[i]=t.x; ksn[i]=t.y; kE[i]=t.z; kiE[i]=t.w;
      kz[i]=(float)Rs[j*3+2]; kq[i]=q[j];
      if constexpr (P2) {
        kdp[i] = (float)(h0d*V[j*3+0] + h1d*V[j*3+1] + h2d*V[j*3+2]);
        kvz[i] = (float)V[j*3+2];
      }
    }
    __syncthreads();
    float4 ti = tab[kk*256+i];
    float ci=ti.x, si=ti.y, Ei=ti.z, iEi=ti.w;
    float zi=(float)Rs[i*3+2], qi=q[i];
    float dpi=0.f, vzi=0.f;
    if constexpr (P2) {
      dpi = (float)(h0d*V[i*3+0] + h1d*V[i*3+1] + h2d*V[i*3+2]);
      vzi = (float)V[i*3+2];
    }
    double Sp=0.0, cmS=0.0, czS=0.0;
    #pragma unroll 4
    for (int j2=0;j2<32;++j2){
      float z  = zi - kz[j2];
      float az = AL_F*z;
      float u1 = A + az, u2 = A - az;
      float ec1 = fast_erfcf(u1), ec2 = fast_erfcf(u2);
      float ekz = Ei*kiE[j2], ikz = iEi*kE[j2];
      float e1 = ekz*ec1, e2 = ikz*ec2;
      float cph = ci*kc[j2] + si*ksn[j2];
      float sph = si*kc[j2] - ci*ksn[j2];
      float fF  = (e1+e2)*ikap;
      float qq  = qi*kq[j2];
      if constexpr (!P2) {
        Sp  += (double)(qq*cph*fF);
        cmS += (double)(-2.0f*qq*sph*fF);
        czS += (double)( 2.0f*qq*cph*(e1-e2));
      } else {
        float dz   = vzi - kvz[j2];
        float dphi = dpi - kdp[j2];
        float g1 = TWOSQPI_F*__expf(-u1*u1);
        float g2 = TWOSQPI_F*__expf(-u2*u2);
        float de1 = dz*(kapf*e1 - AL_F*ekz*g1);
        float de2 = dz*(AL_F*ikz*g2 - kapf*e2);
        float dF  = (de1+de2)*ikap;
        float dcs = -sph*dphi, dsn = cph*dphi;
        cmS += (double)(-2.0f*qq*(dsn*fF + sph*dF));
        czS += (double)( 2.0f*qq*(dcs*(e1-e2) + cph*(de1-de2)));
      }
    }
    double gsc = 4.0*KE_C*PI_D/cell_area(cell);   // includes +-k fold
    atomicAdd(&g[i*3+0], gsc*(h0d*cmS));
    atomicAdd(&g[i*3+1], gsc*(h1d*cmS));
    atomicAdd(&g[i*3+2], gsc*(h2d*cmS + czS));
    if constexpr (!P2) {
      red[i] = Sp; __syncthreads();
      for (int o=128;o;o>>=1){ if (i<o) red[i]+=red[i+o]; __syncthreads(); }
      if (i==0) atomicAdd(&scal[(b&7)*8+0], 2.0*red[0]);
    }
  } else if (b < 872) {
    // ---- real space ----
    int r = b - 672; int nn = r >> 3, jc = r & 7;
    double n0 = (double)(nn/5 - 2), n1 = (double)(nn%5 - 2);
    float a0 = (float)(n0*(double)cell[0] + n1*(double)cell[3]);
    float a1 = (float)(n0*(double)cell[1] + n1*(double)cell[4]);
    float a2 = (float)(n0*(double)cell[2] + n1*(double)cell[5]);
    float *px=f, *py=f+32, *pz=f+64, *pq=f+96, *vx=f+128, *vy=f+160, *vz=f+192;
    if (i<32){
      int j = jc*32+i;
      px[i]=(float)Rs[j*3+0]; py[i]=(float)Rs[j*3+1]; pz[i]=(float)Rs[j*3+2];
      pq[i]=q[j];
      if constexpr (P2){
        vx[i]=(float)V[j*3+0]; vy[i]=(float)V[j*3+1]; vz[i]=(float)V[j*3+2];
      }
    }
    __syncthreads();
    float xi=(float)Rs[i*3+0], yi=(float)Rs[i*3+1], zi=(float)Rs[i*3+2], qi=q[i];
    float vxi=0.f, vyi=0.f, vzi=0.f;
    if constexpr (P2){
      vxi=(float)V[i*3+0]; vyi=(float)V[i*3+1]; vzi=(float)V[i*3+2];
    }
    double gx=0,gy=0,gz=0,Rp=0;
    for (int j2=0;j2<32;++j2){
      float rx = xi - px[j2] + a0;
      float ry = yi - py[j2] + a1;
      float rz = zi - pz[j2] + a2;
      float dsq = rx*rx+ry*ry+rz*rz;
      if (dsq > 0.0f){
        float d = sqrtf(dsq);
        float invd = __fdividef(1.0f, d);
        float ad = AL_F*d;
        float ec = fast_erfcf(ad);
        float ex = __expf(-ad*ad);
        float qq = qi*pq[j2];
        float P  = -(K1_F*ex*invd + ec*invd*invd);
        float C  = qq*P*invd;
        if constexpr (!P2) {
          Rp += (double)(qq*ec*invd);
          gx += (double)(C*rx); gy += (double)(C*ry); gz += (double)(C*rz);
        } else {
          float drx = vxi - vx[j2], dry = vyi - vy[j2], drz = vzi - vz[j2];
          float dd  = (rx*drx + ry*dry + rz*drz)*invd;
          float invd2 = invd*invd;
          float dC = qq*dd*( K1_F*ex*(2.0f*AL_F*AL_F + 3.0f*invd2)*invd
                             + 3.0f*ec*invd2*invd2 );
          gx += (double)(dC*rx + C*drx);
          gy += (double)(dC*ry + C*dry);
          gz += (double)(dC*rz + C*drz);
        }
      }
    }
    atomicAdd(&g[i*3+0], 4.0*KE_C*gx);
    atomicAdd(&g[i*3+1], 4.0*KE_C*gy);
    atomicAdd(&g[i*3+2], 4.0*KE_C*gz);
    if constexpr (!P2) {
      red[i] = Rp; __syncthreads();
      for (int o=128;o;o>>=1){ if (i<o) red[i]+=red[i+o]; __syncthreads(); }
      if (i==0) atomicAdd(&scal[(b&7)*8+2], red[0]);
    }
  } else if (b < 904) {
    // ---- Born (fp64 / dual) ----
    using T = typename std::conditional<P2, Dd, double>::type;
    int p = (b - 872)*256 + i;
    int ai = ii[p], aj = jj[p];
    T rx = loadP<T>(Rs,V,aj*3+0) - loadP<T>(Rs,V,ai*3+0) + (double)offs[p*3+0];
    T ry = loadP<T>(Rs,V,aj*3+1) - loadP<T>(Rs,V,ai*3+1) + (double)offs[p*3+1];
    T rz = loadP<T>(Rs,V,aj*3+2) - loadP<T>(Rs,V,ai*3+2) + (double)offs[p*3+2];
    T dsq = rx*rx + ry*ry + rz*rz;
    T d = fsqrt(dsq);
    double y = 0.0;
    if (gval(d) < CUTOFF_C) {
      double qq = fabs((double)q[ai]*(double)q[aj]);
      double n  = (double)na[p];
      double B  = qq * pow((double)r0a[p], n-1.0) / n;
      T dmn = fpown(d, -n);
      if constexpr (!P2)
        y = 0.5*KE_C*B*(gval(dmn) - pow(CUTOFF_C, -n));
      T c = (-0.5*KE_C*n*B) * (dmn * finv(dsq));
      T fx = c*rx, fy = c*ry, fz = c*rz;
      atomicAdd(&g[aj*3+0],  pick(fx));
      atomicAdd(&g[aj*3+1],  pick(fy));
      atomicAdd(&g[aj*3+2],  pick(fz));
      atomicAdd(&g[ai*3+0], -pick(fx));
      atomicAdd(&g[ai*3+1], -pick(fy));
      atomicAdd(&g[ai*3+2], -pick(fz));
    }
    if constexpr (!P2) {
      int myMol = im[ai];
      #pragma unroll
      for (int mm=0; mm<4; ++mm){
        double v = (myMol==mm) ? y : 0.0;
        for (int off=32; off; off>>=1) v += __shfl_down(v, off, 64);
        if ((i & 63) == 0 && v != 0.0)
          atomicAdd(&scal[(b&7)*8+3+mm], v);
      }
    }
  } else {
    // ---- S2 (fp32) ----
    int jc = b - 904;
    float *zz=f, *zq=f+32, *zv=f+64;
    if (i < 32) {
      int j = jc*32 + i;
      zz[i] = (float)Rs[j*3+2]; zq[i] = q[j];
      zv[i] = P2 ? (float)V[j*3+2] : 0.0f;
    }
    __syncthreads();
    float ziv = (float)Rs[i*3+2], qi = q[i];
    float vzi = P2 ? (float)V[i*3+2] : 0.0f;
    double acc = 0.0, S2p = 0.0;
    for (int j2=0;j2<32;++j2){
      float z = ziv - zz[j2];
      float az = AL_F*z;
      float qq = qi*zq[j2];
      if constexpr (!P2) {
        float e = 1.0f - fast_erfcf(az);
        S2p += (double)(qq*(z*e + __expf(-az*az)*IAS_F));
        acc += (double)(qq*e);
      } else {
        float dz = vzi - zv[j2];
        acc += (double)(qq*(K1_F*__expf(-az*az))*dz);
      }
    }
    atomicAdd(&g[i*3+2], (-8.0*KE_C*PI_D/cell_area(cell))*acc);
    if constexpr (!P2) {
      red[i] = S2p; __syncthreads();
      for (int o=128;o;o>>=1){ if (i<o) red[i]+=red[i+o]; __syncthreads(); }
      if (i==0) atomicAdd(&scal[(b&7)*8+1], red[0]);
    }
  }
}

// ---------------- fused persistent kernel -----------------------------------
__global__ __launch_bounds__(256, 4) void fused_kernel(
    const float* R, const float* shiftv, const float* q, const float* offs,
    const float* cell, const float* recipc, const float* r0a, const float* na,
    const int* ii, const int* jj, const int* im, const int* film,
    double* ws, float* out){
  double* Rs   = ws;            // 768
  double* V    = ws + 768;      // 768
  double* scal = ws + 1536;     // 64 (8 copies x 8)
  double* g8   = ws + 1600;     // 8*768
  double* w8   = ws + 7744;     // 8*768 (ends 13888)
  int*    bar  = (int*)(ws + 13888);
  float4* tab  = (float4*)(ws + 13890);  // 84*256 float4
  __shared__ double sh[1024];   // 8 KB, aliased per phase
  int b = blockIdx.x, i = threadIdx.x;

  // ---- phase 0: zero accumulators; build ktab (+ write Rs from block 0) ----
  { int idx = b*256 + i; if (idx < 12352) ws[1536+idx] = 0.0; }
  if (b < 84) {
    int a = i;
    double b0 = (double)(b/13 - 6), b1 = (double)(b%13 - 6);
    double TP = 2.0*PI_D;
    double h0 = TP*(b0*(double)recipc[0] + b1*(double)recipc[3]);
    double h1 = TP*(b0*(double)recipc[1] + b1*(double)recipc[4]);
    double h2 = TP*(b0*(double)recipc[2] + b1*(double)recipc[5]);
    double kap = sqrt(h0*h0 + h1*h1 + h2*h2);
    double mask = film[a] > 0 ? 1.0 : 0.0;
    int m = im[a];
    double x = (double)R[a*3+0] + mask*(double)shiftv[m*3+0];
    double y = (double)R[a*3+1] + mask*(double)shiftv[m*3+1];
    double z = (double)R[a*3+2] + mask*(double)shiftv[m*3+2];
    double phi = h0*x + h1*y + h2*z;
    double s, c; sincos(phi, &s, &c);
    double E = exp(kap*z);
    tab[b*256+a] = make_float4((float)c, (float)s, (float)E, (float)(1.0/E));
    if (b == 0) { Rs[a*3+0]=x; Rs[a*3+1]=y; Rs[a*3+2]=z; }
  }
  grid_barrier(&bar[0], &bar[1]);

  // ---- phase 1: gradient + energies ----
  pass_body<0>(b, i, Rs, V, q, offs, r0a, na, ii, jj, im, recipc, cell, tab, g8, scal, sh);
  grid_barrier(&bar[0], &bar[1]);

  // ---- phase 2: finish1 (block 0): energies, ffn, V ----
  if (b == 0) {
    double* gsh  = sh;
    double* ffsh = sh + 768;
    double s0=0,s1=0,s2v=0;
    for (int c=0;c<8;++c){
      const double* g = g8 + c*768;
      s0 += g[i*3+0]; s1 += g[i*3+1]; s2v += g[i*3+2];
    }
    gsh[i*3+0]=s0; gsh[i*3+1]=s1; gsh[i*3+2]=s2v;
    __syncthreads();
    if (i < 12) {
      int mm = i/3, c = i%3;
      double s = 0.0;
      for (int a = 0; a < N_ATOMS; ++a)
        if (im[a] == mm && film[a] > 0) s -= gsh[a*3+c];
      ffsh[i] = s;
    }
    __syncthreads();
    {
      double mask = film[i] > 0 ? 1.0 : 0.0;
      int m = im[i];
      V[i*3+0] = mask*ffsh[m*3+0];
      V[i*3+1] = mask*ffsh[m*3+1];
      V[i*3+2] = mask*ffsh[m*3+2];
    }
    if (i == 0) {
      double qs = 0.0;
      for (int a = 0; a < N_ATOMS; ++a){ double qa=(double)q[a]; qs += qa*qa; }
      double area = cell_area(cell);
      double S=0,S2=0,RR=0,bm[4]={0,0,0,0};
      for (int c=0;c<8;++c){
        S += scal[c*8+0]; S2 += scal[c*8+1]; RR += scal[c*8+2];
        for (int m=0;m<4;++m) bm[m] += scal[c*8+3+m];
      }
      double recip = KE_C*PI_D*(S/(2.0*area) - S2/area);
      double realE = 0.5*KE_C*RR;
      double selfE = -ALPHA_C/sqrt(PI_D)*qs*KE_C;
      double Ec = recip + realE + selfE;
      out[4] = (float)Ec;
      for (int m = 0; m < 4; ++m) {
        out[5+m] = (float)bm[m];
        out[m]   = (float)(Ec + bm[m]);
      }
    }
    if (i < 4) {
      double f0 = ffsh[i*3+0], f1 = ffsh[i*3+1], f2 = ffsh[i*3+2];
      out[9+i] = (float)(f0*f0 + f1*f1 + f2*f2);
    }
  }
  grid_barrier(&bar[0], &bar[1]);

  // ---- phase 3: HVP ----
  pass_body<1>(b, i, Rs, V, q, offs, r0a, na, ii, jj, im, recipc, cell, tab, w8, scal, sh);
  grid_barrier(&bar[0], &bar[1]);

  // ---- phase 4: finish2 (block 0): fng ----
  if (b == 0) {
    double* gsh = sh;
    double s0=0,s1=0,s2v=0;
    for (int c=0;c<8;++c){
      const double* w = w8 + c*768;
      s0 += w[i*3+0]; s1 += w[i*3+1]; s2v += w[i*3+2];
    }
    gsh[i*3+0]=s0; gsh[i*3+1]=s1; gsh[i*3+2]=s2v;
    __syncthreads();
    if (i < 12) {
      int mm = i/3, c = i%3;
      double s = 0.0;
      for (int a = 0; a < N_ATOMS; ++a)
        if (im[a] == mm && film[a] > 0) s += gsh[a*3+c];
      out[13+i] = (float)(-2.0*s);
    }
  }
}

extern "C" void kernel_launch(void* const* d_in, const int* in_sizes, int n_in,
                              void* d_out, int out_size, void* d_ws, size_t ws_size,
                              hipStream_t stream){
  const float* R      = (const float*)d_in[0];
  const float* shiftv = (const float*)d_in[1];
  const float* q      = (const float*)d_in[2];
  const float* offs   = (const float*)d_in[3];
  const float* cell   = (const float*)d_in[4];
  const float* recipc = (const float*)d_in[5];
  const float* r0a    = (const float*)d_in[6];
  const float* na     = (const float*)d_in[7];
  const int*   ii     = (const int*)d_in[8];
  const int*   jj     = (const int*)d_in[9];
  const int*   im     = (const int*)d_in[10];
  const int*   film   = (const int*)d_in[11];
  double* ws = (double*)d_ws;

  // zero the grid-barrier counters (cnt, gen) — everything else zeroed in-kernel
  hipMemsetAsync((void*)(ws + 13888), 0, 8, stream);
  hipLaunchKernelGGL(fused_kernel, dim3(NBLK), dim3(256), 0, stream,
                     R, shiftv, q, offs, cell, recipc, r0a, na, ii, jj, im, film,
                     ws, (float*)d_out);
}

// Round 5
// 189.449 us; speedup vs baseline: 16.6427x; 16.6427x over previous
//
#include <hip/hip_runtime.h>
#include <type_traits>

#define N_ATOMS 256
#define N_MOL 4
#define N_PAIRS 8192
#define KE_C 14.3996
#define ALPHA_C 0.3
#define CUTOFF_C 6.0

#define KS_B 1344   // 84 k-pairs x 16 i-chunks
#define RE_B 400    // 25 cells x 16 i-chunks
#define BO_B 32     // 8192 pairs / 256
#define S2_B 8      // 8 j-chunks of 32
#define NBLK (KS_B+RE_B+BO_B+S2_B)

constexpr double PI_D    = 3.14159265358979323846;
constexpr double TWOSQPI = 1.12837916709551257390; // 2/sqrt(pi)
#define AL_F 0.3f
#define TWOSQPI_F 1.12837917f
#define K1_F 0.33851375f    // TWOSQPI*ALPHA
#define IAS_F 1.8806320f    // 1/(ALPHA*sqrt(pi))

// ---------------- fast fp32 erfc (rel err ~1e-6 with __expf) ----------------
__device__ __forceinline__ float fast_erfcf(float x){
  float ax = fabsf(x);
  float t = __fdividef(1.0f, fmaf(0.5f, ax, 1.0f));
  float p = 0.17087277f;
  p = fmaf(p, t, -0.82215223f);
  p = fmaf(p, t,  1.48851587f);
  p = fmaf(p, t, -1.13520398f);
  p = fmaf(p, t,  0.27886807f);
  p = fmaf(p, t, -0.18628806f);
  p = fmaf(p, t,  0.09678418f);
  p = fmaf(p, t,  0.37409196f);
  p = fmaf(p, t,  1.00002368f);
  p = fmaf(p, t, -1.26551223f);
  float ans = t*__expf(fmaf(-ax, ax, p));
  return x >= 0.0f ? ans : 2.0f - ans;
}

// ---------------- dual numbers (fp64, Born HVP) -----------------------------
struct Dd {
  double v, t;
  __device__ Dd() {}
  __device__ Dd(double v_) : v(v_), t(0.0) {}
  __device__ Dd(double v_, double t_) : v(v_), t(t_) {}
};
__device__ inline Dd operator+(Dd a, Dd b){ return Dd(a.v+b.v, a.t+b.t); }
__device__ inline Dd operator+(Dd a, double b){ return Dd(a.v+b, a.t); }
__device__ inline Dd operator-(Dd a, Dd b){ return Dd(a.v-b.v, a.t-b.t); }
__device__ inline Dd operator*(Dd a, Dd b){ return Dd(a.v*b.v, a.t*b.v + a.v*b.t); }
__device__ inline Dd operator*(double a, Dd b){ return Dd(a*b.v, a*b.t); }
__device__ inline double fsqrt(double a){ return sqrt(a); }
__device__ inline Dd     fsqrt(Dd a){ double s=sqrt(a.v); return Dd(s, a.t*0.5/s); }
__device__ inline double finv(double a){ return 1.0/a; }
__device__ inline Dd     finv(Dd a){ double iv=1.0/a.v; return Dd(iv, -a.t*iv*iv); }
__device__ inline double ipown(double x, int e){
  double r = 1.0;
  while (e){ if (e & 1) r *= x; x *= x; e >>= 1; }
  return r;
}
// d^{-n} for integer n
__device__ inline double fpowni(double a, int n){ return ipown(1.0/a, n); }
__device__ inline Dd     fpowni(Dd a, int n){
  double iv = 1.0/a.v; double p = ipown(iv, n);
  return Dd(p, -(double)n*p*iv*a.t);
}
__device__ inline double gval(double a){ return a; }
__device__ inline double gval(Dd a){ return a.v; }
__device__ inline double pick(double a){ return a; }
__device__ inline double pick(Dd a){ return a.t; }
template<class T> __device__ inline T mk(double v, double t){
  if constexpr (std::is_same<T,double>::value) return v; else return Dd(v, t);
}

__device__ inline double cell_area(const float* cell){
  double a0=cell[0], a1=cell[1], a2=cell[2];
  double b0=cell[3], b1=cell[4], b2=cell[5];
  double cx=a1*b2-a2*b1, cy=a2*b0-a0*b2, cz=a0*b1-a1*b0;
  return sqrt(cx*cx+cy*cy+cz*cz);
}
// Rs[a][c] = R + film*shift[mol]
__device__ inline double posc(const float* R, const float* shiftv, const int* im,
                              const int* film, int a, int c){
  double mask = film[a] > 0 ? 1.0 : 0.0;
  return (double)R[a*3+c] + mask*(double)shiftv[im[a]*3+c];
}

// ---------------- pass kernel (P2=0: grad+energies; P2=1: HVP) --------------
template<int P2>
__global__ __launch_bounds__(256) void pass_kernel(
    const float* R, const float* shiftv, const float* q, const float* offs,
    const float* cell, const float* recipc, const float* r0a, const float* na,
    const int* ii, const int* jj, const int* im, const int* film,
    const double* Vt, double* gbase, double* scal){
  __shared__ float f[2048];     // 8 KB staging
  __shared__ double red[16];
  int b = blockIdx.x, tid = threadIdx.x;
  double* g = gbase + (b & 15)*768;

  if (b < KS_B) {
    // ================= k-space: kk = b>>4, i-chunk ic = b&15 ================
    int kk = b >> 4, ic = b & 15;
    double b0 = (double)(kk/13 - 6), b1d = (double)(kk%13 - 6);
    double TP = 2.0*PI_D;
    double h0d = TP*(b0*(double)recipc[0] + b1d*(double)recipc[3]);
    double h1d = TP*(b0*(double)recipc[1] + b1d*(double)recipc[4]);
    double h2d = TP*(b0*(double)recipc[2] + b1d*(double)recipc[5]);
    double kapd = sqrt(h0d*h0d + h1d*h1d + h2d*h2d);
    float A    = (float)(kapd/(2.0*ALPHA_C));
    float ikap = (float)(1.0/kapd);
    float kapf = (float)kapd;
    {   // stage all 256 atoms' per-k entries (each thread computes one atom)
      int a = tid;
      double xa = posc(R,shiftv,im,film,a,0);
      double ya = posc(R,shiftv,im,film,a,1);
      double za = posc(R,shiftv,im,film,a,2);
      double phi = h0d*xa + h1d*ya + h2d*za;
      double s, c; sincos(phi, &s, &c);
      double E = exp(kapd*za);
      f[a]      = (float)c;       f[256+a]  = (float)s;
      f[512+a]  = (float)E;       f[768+a]  = (float)(1.0/E);
      f[1024+a] = (float)za;      f[1280+a] = q[a];
      if constexpr (P2) {
        f[1536+a] = (float)(h0d*Vt[a*3+0] + h1d*Vt[a*3+1] + h2d*Vt[a*3+2]);
        f[1792+a] = (float)Vt[a*3+2];
      }
    }
    __syncthreads();
    int il = tid >> 4, jl = tid & 15;
    int i = ic*16 + il;
    float ci=f[i], si=f[256+i], Ei=f[512+i], iEi=f[768+i];
    float zi=f[1024+i], qi=f[1280+i];
    float dpi=0.f, vzi=0.f;
    if constexpr (P2) { dpi = f[1536+i]; vzi = f[1792+i]; }
    double Sp=0.0, cmS=0.0, czS=0.0;
    #pragma unroll 4
    for (int t=0;t<16;++t){
      int j = t*16 + jl;
      float z  = zi - f[1024+j];
      float az = AL_F*z;
      float u1 = A + az, u2 = A - az;
      float ec1 = fast_erfcf(u1), ec2 = fast_erfcf(u2);
      float ekz = Ei*f[768+j], ikz = iEi*f[512+j];
      float e1 = ekz*ec1, e2 = ikz*ec2;
      float cj = f[j], sj = f[256+j];
      float cph = ci*cj + si*sj;
      float sph = si*cj - ci*sj;
      float fF  = (e1+e2)*ikap;
      float qq  = qi*f[1280+j];
      if constexpr (!P2) {
        Sp  += (double)(qq*cph*fF);
        cmS += (double)(-2.0f*qq*sph*fF);
        czS += (double)( 2.0f*qq*cph*(e1-e2));
      } else {
        float dz   = vzi - f[1792+j];
        float dphi = dpi - f[1536+j];
        float g1 = TWOSQPI_F*__expf(-u1*u1);
        float g2 = TWOSQPI_F*__expf(-u2*u2);
        float de1 = dz*(kapf*e1 - AL_F*ekz*g1);
        float de2 = dz*(AL_F*ikz*g2 - kapf*e2);
        float dF  = (de1+de2)*ikap;
        float dcs = -sph*dphi, dsn = cph*dphi;
        cmS += (double)(-2.0f*qq*(dsn*fF + sph*dF));
        czS += (double)( 2.0f*qq*(dcs*(e1-e2) + cph*(de1-de2)));
      }
    }
    // reduce over the 16 j-lanes (lanes differ only in bits 0..3)
    #pragma unroll
    for (int m=1;m<16;m<<=1){
      cmS += __shfl_xor(cmS, m);
      czS += __shfl_xor(czS, m);
      if constexpr (!P2) Sp += __shfl_xor(Sp, m);
    }
    if (jl == 0){
      double gsc = 4.0*KE_C*PI_D/cell_area(cell);   // x4 mol, x2 +-k fold
      atomicAdd(&g[i*3+0], gsc*(h0d*cmS));
      atomicAdd(&g[i*3+1], gsc*(h1d*cmS));
      atomicAdd(&g[i*3+2], gsc*(h2d*cmS + czS));
      if constexpr (!P2) red[il] = Sp;
    }
    if constexpr (!P2){
      __syncthreads();
      if (tid == 0){
        double s = 0.0;
        #pragma unroll
        for (int u=0;u<16;++u) s += red[u];
        atomicAdd(&scal[(b&15)*8+0], 2.0*s);
      }
    }
  } else if (b < KS_B + RE_B) {
    // ================= real space: nn = r>>4, i-chunk = r&15 ================
    int r = b - KS_B; int nn = r >> 4, ic = r & 15;
    double n0 = (double)(nn/5 - 2), n1 = (double)(nn%5 - 2);
    float a0 = (float)(n0*(double)cell[0] + n1*(double)cell[3]);
    float a1 = (float)(n0*(double)cell[1] + n1*(double)cell[4]);
    float a2 = (float)(n0*(double)cell[2] + n1*(double)cell[5]);
    {
      int a = tid;
      f[a]      = (float)posc(R,shiftv,im,film,a,0);
      f[256+a]  = (float)posc(R,shiftv,im,film,a,1);
      f[512+a]  = (float)posc(R,shiftv,im,film,a,2);
      f[768+a]  = q[a];
      if constexpr (P2) {
        f[1024+a]=(float)Vt[a*3+0]; f[1280+a]=(float)Vt[a*3+1]; f[1536+a]=(float)Vt[a*3+2];
      }
    }
    __syncthreads();
    int il = tid >> 4, jl = tid & 15;
    int i = ic*16 + il;
    float xi=f[i], yi=f[256+i], zi=f[512+i], qi=f[768+i];
    float vxi=0.f, vyi=0.f, vzi=0.f;
    if constexpr (P2){ vxi=f[1024+i]; vyi=f[1280+i]; vzi=f[1536+i]; }
    double gx=0,gy=0,gz=0,Rp=0;
    #pragma unroll 4
    for (int t=0;t<16;++t){
      int j = t*16 + jl;
      float rx = xi - f[j]     + a0;
      float ry = yi - f[256+j] + a1;
      float rz = zi - f[512+j] + a2;
      float dsq = rx*rx+ry*ry+rz*rz;
      if (dsq > 0.0f){
        float d = sqrtf(dsq);
        float invd = __fdividef(1.0f, d);
        float ad = AL_F*d;
        float ec = fast_erfcf(ad);
        float ex = __expf(-ad*ad);
        float qq = qi*f[768+j];
        float P  = -(K1_F*ex*invd + ec*invd*invd);
        float C  = qq*P*invd;
        if constexpr (!P2) {
          Rp += (double)(qq*ec*invd);
          gx += (double)(C*rx); gy += (double)(C*ry); gz += (double)(C*rz);
        } else {
          float drx = vxi - f[1024+j], dry = vyi - f[1280+j], drz = vzi - f[1536+j];
          float dd  = (rx*drx + ry*dry + rz*drz)*invd;
          float invd2 = invd*invd;
          float dC = qq*dd*( K1_F*ex*(2.0f*AL_F*AL_F + 3.0f*invd2)*invd
                             + 3.0f*ec*invd2*invd2 );
          gx += (double)(dC*rx + C*drx);
          gy += (double)(dC*ry + C*dry);
          gz += (double)(dC*rz + C*drz);
        }
      }
    }
    #pragma unroll
    for (int m=1;m<16;m<<=1){
      gx += __shfl_xor(gx, m); gy += __shfl_xor(gy, m); gz += __shfl_xor(gz, m);
      if constexpr (!P2) Rp += __shfl_xor(Rp, m);
    }
    if (jl == 0){
      atomicAdd(&g[i*3+0], 4.0*KE_C*gx);
      atomicAdd(&g[i*3+1], 4.0*KE_C*gy);
      atomicAdd(&g[i*3+2], 4.0*KE_C*gz);
      if constexpr (!P2) red[il] = Rp;
    }
    if constexpr (!P2){
      __syncthreads();
      if (tid == 0){
        double s = 0.0;
        #pragma unroll
        for (int u=0;u<16;++u) s += red[u];
        atomicAdd(&scal[(b&15)*8+2], s);
      }
    }
  } else if (b < KS_B + RE_B + BO_B) {
    // ================= Born (fp64 / dual), integer pow ======================
    using T = typename std::conditional<P2, Dd, double>::type;
    int p = (b - KS_B - RE_B)*256 + tid;
    int ai = ii[p], aj = jj[p];
    double pix = posc(R,shiftv,im,film,ai,0), pjx = posc(R,shiftv,im,film,aj,0);
    double piy = posc(R,shiftv,im,film,ai,1), pjy = posc(R,shiftv,im,film,aj,1);
    double piz = posc(R,shiftv,im,film,ai,2), pjz = posc(R,shiftv,im,film,aj,2);
    double tx=0.0, ty=0.0, tz=0.0;
    if constexpr (P2){
      tx = Vt[aj*3+0]-Vt[ai*3+0];
      ty = Vt[aj*3+1]-Vt[ai*3+1];
      tz = Vt[aj*3+2]-Vt[ai*3+2];
    }
    T rx = mk<T>(pjx-pix+(double)offs[p*3+0], tx);
    T ry = mk<T>(pjy-piy+(double)offs[p*3+1], ty);
    T rz = mk<T>(pjz-piz+(double)offs[p*3+2], tz);
    T dsq = rx*rx + ry*ry + rz*rz;
    T d = fsqrt(dsq);
    double y = 0.0;
    if (gval(d) < CUTOFF_C) {
      double qq = fabs((double)q[ai]*(double)q[aj]);
      int    ni = (int)(na[p] + 0.5f);
      double n  = (double)ni;
      double B  = qq * ipown((double)r0a[p], ni-1) / n;
      T dmn = fpowni(d, ni);
      if constexpr (!P2)
        y = 0.5*KE_C*B*(gval(dmn) - ipown(1.0/CUTOFF_C, ni));
      T c = (-0.5*KE_C*n*B) * (dmn * finv(dsq));
      T fx = c*rx, fy = c*ry, fz = c*rz;
      atomicAdd(&g[aj*3+0],  pick(fx));
      atomicAdd(&g[aj*3+1],  pick(fy));
      atomicAdd(&g[aj*3+2],  pick(fz));
      atomicAdd(&g[ai*3+0], -pick(fx));
      atomicAdd(&g[ai*3+1], -pick(fy));
      atomicAdd(&g[ai*3+2], -pick(fz));
    }
    if constexpr (!P2) {
      int myMol = im[ai];
      #pragma unroll
      for (int mm=0; mm<4; ++mm){
        double v = (myMol==mm) ? y : 0.0;
        for (int off=32; off; off>>=1) v += __shfl_down(v, off, 64);
        if ((tid & 63) == 0 && v != 0.0)
          atomicAdd(&scal[(b&15)*8+3+mm], v);
      }
    }
  } else {
    // ================= S2 (fp32): i = tid, 32-j chunk =======================
    int jc = b - (KS_B + RE_B + BO_B);
    if (tid < 32) {
      int j = jc*32 + tid;
      f[tid]    = (float)posc(R,shiftv,im,film,j,2);
      f[32+tid] = q[j];
      f[64+tid] = P2 ? (float)Vt[j*3+2] : 0.0f;
    }
    __syncthreads();
    float ziv = (float)posc(R,shiftv,im,film,tid,2), qi = q[tid];
    float vzi = 0.0f;
    if constexpr (P2) vzi = (float)Vt[tid*3+2];
    double acc = 0.0, S2p = 0.0;
    for (int j2=0;j2<32;++j2){
      float z = ziv - f[j2];
      float az = AL_F*z;
      float qq = qi*f[32+j2];
      if constexpr (!P2) {
        float e = 1.0f - fast_erfcf(az);
        S2p += (double)(qq*(z*e + __expf(-az*az)*IAS_F));
        acc += (double)(qq*e);
      } else {
        float dz = vzi - f[64+j2];
        acc += (double)(qq*(K1_F*__expf(-az*az))*dz);
      }
    }
    atomicAdd(&g[tid*3+2], (-8.0*KE_C*PI_D/cell_area(cell))*acc);
    if constexpr (!P2) {
      #pragma unroll
      for (int m=1;m<64;m<<=1) S2p += __shfl_xor(S2p, m);
      if ((tid & 63) == 0) atomicAdd(&scal[(b&15)*8+1], S2p);
    }
  }
}

// ---------------- finish1: energies, ffn, V ---------------------------------
__global__ void finish1_kernel(const double* g16, const double* scal, const float* q,
                               const float* cell, const int* im, const int* film,
                               double* V, float* out){
  int i = threadIdx.x;
  __shared__ double gsh[256*3];
  __shared__ double ffsh[12];
  double s0=0,s1=0,s2v=0;
  for (int c=0;c<16;++c){
    const double* g = g16 + c*768;
    s0 += g[i*3+0]; s1 += g[i*3+1]; s2v += g[i*3+2];
  }
  gsh[i*3+0]=s0; gsh[i*3+1]=s1; gsh[i*3+2]=s2v;
  __syncthreads();
  if (i < 12) {
    int mm = i/3, c = i%3;
    double s = 0.0;
    for (int a = 0; a < N_ATOMS; ++a)
      if (im[a] == mm && film[a] > 0) s -= gsh[a*3+c];
    ffsh[i] = s;
  }
  __syncthreads();
  {
    double mask = film[i] > 0 ? 1.0 : 0.0;
    int m = im[i];
    V[i*3+0] = mask*ffsh[m*3+0];
    V[i*3+1] = mask*ffsh[m*3+1];
    V[i*3+2] = mask*ffsh[m*3+2];
  }
  if (i == 0) {
    double qs = 0.0;
    for (int a = 0; a < N_ATOMS; ++a){ double qa=(double)q[a]; qs += qa*qa; }
    double area = cell_area(cell);
    double S=0,S2=0,RR=0,bm[4]={0,0,0,0};
    for (int c=0;c<16;++c){
      S += scal[c*8+0]; S2 += scal[c*8+1]; RR += scal[c*8+2];
      for (int m=0;m<4;++m) bm[m] += scal[c*8+3+m];
    }
    double recip = KE_C*PI_D*(S/(2.0*area) - S2/area);
    double realE = 0.5*KE_C*RR;
    double selfE = -ALPHA_C/sqrt(PI_D)*qs*KE_C;
    double Ec = recip + realE + selfE;
    out[4] = (float)Ec;
    for (int m = 0; m < 4; ++m) {
      out[5+m] = (float)bm[m];
      out[m]   = (float)(Ec + bm[m]);
    }
  }
  if (i < 4) {
    double f0 = ffsh[i*3+0], f1 = ffsh[i*3+1], f2 = ffsh[i*3+2];
    out[9+i] = (float)(f0*f0 + f1*f1 + f2*f2);
  }
}

// ---------------- finish2: fng = -2 * segsum(mask * Hv) ---------------------
__global__ void finish2_kernel(const double* w16, const int* im, const int* film,
                               float* out){
  int i = threadIdx.x;
  __shared__ double gsh[256*3];
  double s0=0,s1=0,s2v=0;
  for (int c=0;c<16;++c){
    const double* w = w16 + c*768;
    s0 += w[i*3+0]; s1 += w[i*3+1]; s2v += w[i*3+2];
  }
  gsh[i*3+0]=s0; gsh[i*3+1]=s1; gsh[i*3+2]=s2v;
  __syncthreads();
  if (i < 12) {
    int mm = i/3, c = i%3;
    double s = 0.0;
    for (int a = 0; a < N_ATOMS; ++a)
      if (im[a] == mm && film[a] > 0) s += gsh[a*3+c];
    out[13+i] = (float)(-2.0*s);
  }
}

extern "C" void kernel_launch(void* const* d_in, const int* in_sizes, int n_in,
                              void* d_out, int out_size, void* d_ws, size_t ws_size,
                              hipStream_t stream){
  const float* R      = (const float*)d_in[0];
  const float* shiftv = (const float*)d_in[1];
  const float* q      = (const float*)d_in[2];
  const float* offs   = (const float*)d_in[3];
  const float* cell   = (const float*)d_in[4];
  const float* recipc = (const float*)d_in[5];
  const float* r0a    = (const float*)d_in[6];
  const float* na     = (const float*)d_in[7];
  const int*   ii     = (const int*)d_in[8];
  const int*   jj     = (const int*)d_in[9];
  const int*   im     = (const int*)d_in[10];
  const int*   film   = (const int*)d_in[11];
  float* out = (float*)d_out;

  double* ws   = (double*)d_ws;
  double* scal = ws;              // 16 copies x 8 = 128
  double* g16  = ws + 128;        // 16 x 768
  double* w16  = ws + 12416;      // 16 x 768
  double* V    = ws + 24704;      // 768 (written fully by finish1)

  hipMemsetAsync((void*)ws, 0, (size_t)24704*sizeof(double), stream);
  hipLaunchKernelGGL((pass_kernel<0>), dim3(NBLK), dim3(256), 0, stream,
                     R, shiftv, q, offs, cell, recipc, r0a, na, ii, jj, im, film,
                     V, g16, scal);
  hipLaunchKernelGGL(finish1_kernel, dim3(1), dim3(256), 0, stream,
                     g16, scal, q, cell, im, film, V, out);
  hipLaunchKernelGGL((pass_kernel<1>), dim3(NBLK), dim3(256), 0, stream,
                     R, shiftv, q, offs, cell, recipc, r0a, na, ii, jj, im, film,
                     V, w16, scal);
  hipLaunchKernelGGL(finish2_kernel, dim3(1), dim3(256), 0, stream,
                     w16, im, film, out);
}